// Round 15
// baseline (2937.520 us; speedup 1.0000x reference)
//
#include <hip/hip_runtime.h>

// ---- problem constants ----
namespace {
constexpr int nT = 64;
constexpr int nK = 7;
constexpr long N_PSI = 1123776;
constexpr long SZ_WHH = 1048576;       // psi region 0: (1024,1024)
constexpr long REST_SZ = 75200;        // per-sample remaining psi elems
constexpr long R_BH = 0;               // (1024,)
constexpr long R_WIH = 1024;           // (8,1024)
constexpr long R_C = 9216;             // (1024,64)
constexpr long R_D = 74752;            // (8,56)
constexpr int NCH = 16;                // h-chunks per step
constexpr long PHALF = (long)NCH * 64 * 1024;  // one partial buffer (floats)
}

typedef __attribute__((ext_vector_type(4))) unsigned short us4;
typedef __attribute__((ext_vector_type(2))) unsigned short us2;

__device__ __forceinline__ float b2f(unsigned short u) {
  return __uint_as_float(((unsigned int)u) << 16);
}
__device__ __forceinline__ unsigned short f2b(float f) {
  unsigned int u = __float_as_uint(f);
  return (unsigned short)((u + 0x7fffu + ((u >> 16) & 1u)) >> 16);
}
__device__ __forceinline__ float sigm(float x) { return 1.f / (1.f + __expf(-x)); }

// ---------- one-time: transpose (rows,cols) fp32 -> bf16 out[c*rows + r] ----------
__global__ void transpose_bf16_k(const float* __restrict__ in, unsigned short* __restrict__ out,
                                 int rows, int cols) {
  __shared__ float tile[32][33];
  int x = blockIdx.x * 32 + threadIdx.x;
  int y = blockIdx.y * 32 + threadIdx.y;
  #pragma unroll
  for (int i = 0; i < 32; i += 8)
    if ((y + i) < rows && x < cols) tile[threadIdx.y + i][threadIdx.x] = in[(long)(y + i) * cols + x];
  __syncthreads();
  x = blockIdx.y * 32 + threadIdx.x;
  y = blockIdx.x * 32 + threadIdx.y;
  #pragma unroll
  for (int i = 0; i < 32; i += 8)
    if ((y + i) < cols && x < rows) out[(long)(y + i) * rows + x] = f2b(tile[threadIdx.x][threadIdx.y + i]);
}

__global__ void cvt_bf16_k(const float* __restrict__ in, unsigned short* __restrict__ out, long n) {
  long i = (long)blockIdx.x * 256 + threadIdx.x;
  if (i < n) out[i] = f2b(in[i]);
}

// ---------- bulk: encoder gx ----------
__global__ __launch_bounds__(256) void enc_gx_k(const float* __restrict__ outputs,
                                                const unsigned short* __restrict__ WtWihB,
                                                const float* __restrict__ bih,
                                                unsigned short* __restrict__ gxE) {
  int g0 = blockIdx.x * 256;
  int btg = blockIdx.y;
  __shared__ unsigned short ws[64 * 256];
  __shared__ float xs[64][64];
  for (int i = threadIdx.x; i < 64 * 256; i += 256)
    ws[i] = WtWihB[(long)(i >> 8) * 3072 + g0 + (i & 255)];
  for (int i = threadIdx.x; i < 64 * 64; i += 256) {
    int idx = btg * 64 + (i >> 6);
    int t = idx >> 6, b = idx & 63;
    xs[i >> 6][i & 63] = outputs[((long)b * nT + t) * 64 + (i & 63)];
  }
  __syncthreads();
  float bihv = bih[g0 + threadIdx.x];
  for (int j = 0; j < 64; ++j) {
    int idx = btg * 64 + j;
    float acc = bihv;
    #pragma unroll 8
    for (int i = 0; i < 64; ++i) acc += xs[j][i] * b2f(ws[i * 256 + threadIdx.x]);
    gxE[(long)idx * 3072 + g0 + threadIdx.x] = f2b(acc);
  }
}

// ---------- bulk: decoder gx ----------
__global__ __launch_bounds__(256) void dec_gx_k(const float* __restrict__ inputs,
                                                const float* __restrict__ gWih,
                                                const float* __restrict__ gbias,
                                                unsigned short* __restrict__ gxD) {
  int g0 = blockIdx.x * 256;
  int btg = blockIdx.y;
  __shared__ float ws[8][256];
  __shared__ float xs[64][8];
  for (int i = threadIdx.x; i < 8 * 256; i += 256)
    ws[i >> 8][i & 255] = gWih[(long)(i >> 8) * 2048 + g0 + (i & 255)];
  for (int i = threadIdx.x; i < 64 * 8; i += 256) {
    int idx = btg * 64 + (i >> 3);
    int t = idx >> 6, b = idx & 63;
    xs[i >> 3][i & 7] = inputs[((long)b * nT + t) * 8 + (i & 7)];
  }
  __syncthreads();
  float bv = gbias[g0 + threadIdx.x];
  for (int j = 0; j < 64; ++j) {
    int idx = btg * 64 + j;
    float acc = bv;
    #pragma unroll
    for (int i = 0; i < 8; ++i) acc += xs[j][i] * ws[i][threadIdx.x];
    gxD[(long)idx * 2048 + g0 + threadIdx.x] = f2b(acc);
  }
}

// ---------- bulk: x @ Wih_b per sample ----------
__global__ __launch_bounds__(256) void xW_k(const float* __restrict__ inputs,
                                            const float* __restrict__ Rest,
                                            unsigned short* __restrict__ xWb) {
  int k0 = blockIdx.x * 256;
  int b = blockIdx.y;
  __shared__ float ws[8][256];
  __shared__ float xs[64][8];
  const float* RB = Rest + (long)b * REST_SZ + R_WIH;
  for (int i = threadIdx.x; i < 8 * 256; i += 256)
    ws[i >> 8][i & 255] = RB[(long)(i >> 8) * 1024 + k0 + (i & 255)];
  for (int i = threadIdx.x; i < 64 * 8; i += 256)
    xs[i >> 3][i & 7] = inputs[((long)b * nT + (i >> 3)) * 8 + (i & 7)];
  __syncthreads();
  for (int t = 0; t < 64; ++t) {
    float acc = 0.f;
    #pragma unroll
    for (int i = 0; i < 8; ++i) acc += xs[t][i] * ws[i][threadIdx.x];
    xWb[((long)t * 64 + b) * 1024 + k0 + threadIdx.x] = f2b(acc);
  }
}

// ---------- encoder step: 512 threads, balanced phase B ----------
__global__ __launch_bounds__(512, 2) void enc_step4_k(
    const unsigned short* __restrict__ W,       // [1024][3072] bf16 enc_Whh^T (r|z|n)
    const unsigned short* __restrict__ gxE,     // [T][B][3072] bf16 (incl bih)
    const float* __restrict__ bhh,
    float* __restrict__ hEnc,                   // [B][1024] running h
    const float* __restrict__ pRr, const float* __restrict__ pZr, const float* __restrict__ pNr,
    float* __restrict__ pRw, float* __restrict__ pZw, float* __restrict__ pNw,
    int t) {
  int c = blockIdx.x & (NCH - 1);
  int sp = blockIdx.x >> 4;
  int b0 = sp * 2, b1 = b0 + 1;
  __shared__ float h0s[64], h1s[64];
  __shared__ float red[3][4][128];
  int v = threadIdx.x;
  {
    int q = v >> 7, idx = v & 127;
    int bb = (idx >> 6) ? b1 : b0;
    int e = c * 64 + (idx & 63);
    float sr = 0.f, sz = 0.f, sn = 0.f;
    if (t > 0) {
      #pragma unroll
      for (int cc = q * 4; cc < q * 4 + 4; ++cc) {
        long base = ((long)cc * 64 + bb) * 1024 + e;
        sr += pRr[base]; sz += pZr[base]; sn += pNr[base];
      }
    }
    red[0][q][idx] = sr; red[1][q][idx] = sz; red[2][q][idx] = sn;
  }
  __syncthreads();
  if (v < 128) {
    int hi = v >> 6;
    int bb = hi ? b1 : b0;
    int e = c * 64 + (v & 63);
    float sr = red[0][0][v] + red[0][1][v] + red[0][2][v] + red[0][3][v];
    float sz = red[1][0][v] + red[1][1][v] + red[1][2][v] + red[1][3][v];
    float sn = red[2][0][v] + red[2][1][v] + red[2][2][v] + red[2][3][v];
    long gb = ((long)t * 64 + bb) * 3072;
    float xr = b2f(gxE[gb + e]), xz = b2f(gxE[gb + 1024 + e]), xn = b2f(gxE[gb + 2048 + e]);
    float hr = sr + bhh[e], hz = sz + bhh[1024 + e], hn = sn + bhh[2048 + e];
    float r = sigm(xr + hr);
    float z = sigm(xz + hz);
    float n = tanhf(xn + r * hn);
    float hold = (t > 0) ? hEnc[(long)bb * 1024 + e] : 0.f;
    float hnew = (1.f - z) * n + z * hold;
    hEnc[(long)bb * 1024 + e] = hnew;
    if (hi) h1s[v & 63] = hnew; else h0s[v & 63] = hnew;
  }
  __syncthreads();
  // phase B (balanced): every thread: 4 rz-cols (us4) + 2 n-cols (us2), both samples
  if (t < nT - 1) {
    int c4 = v * 4;                 // 0..2047 over r|z
    int c2 = v * 2;                 // 0..1023 over n
    float g0a[4] = {}, g1a[4] = {};
    float n0a[2] = {}, n1a[2] = {};
    const unsigned short* Wg = W + (long)(c * 64) * 3072 + c4;
    const unsigned short* Wn = W + (long)(c * 64) * 3072 + 2048 + c2;
    #pragma unroll 4
    for (int j = 0; j < 64; ++j) {
      us4 wg = *(const us4*)(Wg + (long)j * 3072);
      us2 wn = *(const us2*)(Wn + (long)j * 3072);
      float hv0 = h0s[j], hv1 = h1s[j];
      #pragma unroll
      for (int q = 0; q < 4; ++q) {
        float f = b2f(wg[q]);
        g0a[q] += hv0 * f; g1a[q] += hv1 * f;
      }
      float f0 = b2f(wn[0]), f1 = b2f(wn[1]);
      n0a[0] += hv0 * f0; n0a[1] += hv0 * f1;
      n1a[0] += hv1 * f0; n1a[1] += hv1 * f1;
    }
    float* Pg = (c4 < 1024) ? pRw : pZw;
    int gcol = c4 & 1023;
    long i0 = ((long)c * 64 + b0) * 1024;
    long i1 = i0 + 1024;
    *(float4*)(Pg + i0 + gcol) = make_float4(g0a[0], g0a[1], g0a[2], g0a[3]);
    *(float4*)(Pg + i1 + gcol) = make_float4(g1a[0], g1a[1], g1a[2], g1a[3]);
    *(float2*)(pNw + i0 + c2) = make_float2(n0a[0], n0a[1]);
    *(float2*)(pNw + i1 + c2) = make_float2(n1a[0], n1a[1]);
  }
}

// ---------- fused latent + hypernet layers 1-2 ----------
__global__ __launch_bounds__(256) void latent_hyper_k(
    const float* __restrict__ h_enc,
    const float* __restrict__ to_mu, const float* __restrict__ to_lsig,
    const float* __restrict__ lsig_bias, const float* __restrict__ eps,
    const float* __restrict__ W1, const float* __restrict__ b1,
    const float* __restrict__ W2, const float* __restrict__ b2,
    float* __restrict__ out_mu, float* __restrict__ out_lsig,
    float* __restrict__ a2out) {
  int b = blockIdx.x;
  __shared__ float hs[1024];
  __shared__ float zv[8];
  __shared__ float a1[1024];
  for (int i = threadIdx.x; i < 1024; i += 256) hs[i] = h_enc[b * 1024 + i];
  __syncthreads();
  int g = threadIdx.x >> 5, s = threadIdx.x & 31;
  if (g < nK) {
    float am = 0.f, as_ = 0.f;
    for (int h = s; h < 1024; h += 32) {
      float hv = hs[h];
      am += hv * to_mu[h * nK + g];
      as_ += hv * to_lsig[h * nK + g];
    }
    #pragma unroll
    for (int m = 16; m >= 1; m >>= 1) { am += __shfl_xor(am, m); as_ += __shfl_xor(as_, m); }
    if (s == 0) {
      float ls = as_ + lsig_bias[g];
      out_mu[b * nK + g] = am;
      out_lsig[b * nK + g] = ls;
      zv[g] = am + eps[b * nK + g] * __expf(ls);
    }
  }
  __syncthreads();
  for (int j = threadIdx.x; j < 1024; j += 256) {
    float acc = b1[j];
    #pragma unroll
    for (int i = 0; i < nK; ++i) acc += zv[i] * W1[i * 1024 + j];
    a1[j] = tanhf(acc);
  }
  __syncthreads();
  int l = threadIdx.x >> 3, s8 = threadIdx.x & 7;
  if (l < 30) {
    float acc = 0.f;
    for (int j = s8; j < 1024; j += 8) acc += a1[j] * W2[j * 30 + l];
    acc += __shfl_xor(acc, 4);
    acc += __shfl_xor(acc, 2);
    acc += __shfl_xor(acc, 1);
    if (s8 == 0) a2out[b * 30 + l] = acc + b2[l];
  }
}

// ---------- fused psi Whh: 1 col/thread, 4-sample-group scales (r14) ----------
__global__ __launch_bounds__(256) void psi_q8_k(
    const float* __restrict__ a2, const float* __restrict__ W3, const float* __restrict__ b3,
    char* __restrict__ Q8, float* __restrict__ sdec /*[16][1024][16]*/) {
  __shared__ float sa[64 * 30];
  for (int i = threadIdx.x; i < 64 * 30; i += 256) sa[i] = a2[i];
  int h = blockIdx.x >> 2, q4 = blockIdx.x & 3;
  int wv = threadIdx.x >> 6, lane = threadIdx.x & 63;
  int g = q4 * 4 + wv;
  long n0 = (long)h * 1024 + q4 * 256 + threadIdx.x;
  float w[30];
  #pragma unroll
  for (int l = 0; l < 30; ++l) w[l] = W3[(long)l * N_PSI + n0];
  float bb = b3[n0];
  __syncthreads();
  for (int bq = 0; bq < 16; ++bq) {
    float vv[4];
    #pragma unroll
    for (int s = 0; s < 4; ++s) {
      int b = bq * 4 + s;
      float a0 = bb;
      const float* ab = &sa[b * 30];
      #pragma unroll
      for (int l = 0; l < 30; ++l) a0 += ab[l] * w[l];
      vv[s] = a0;
    }
    float m = fmaxf(fmaxf(fabsf(vv[0]), fabsf(vv[1])), fmaxf(fabsf(vv[2]), fabsf(vv[3])));
    #pragma unroll
    for (int d = 32; d >= 1; d >>= 1) m = fmaxf(m, __shfl_xor(m, d));
    float inv = (m > 0.f) ? 127.f / m : 0.f;
    #pragma unroll
    for (int s = 0; s < 4; ++s) {
      int q = __float2int_rn(vv[s] * inv);
      q = min(127, max(-127, q));
      Q8[(long)(bq * 4 + s) * SZ_WHH + n0] = (char)q;
    }
    if (lane == 0) sdec[((long)bq * 1024 + h) * 16 + g] = m * (1.f / 127.f);
  }
}

// ---------- psi rest region (fp32) ----------
__global__ __launch_bounds__(256) void psi_rest_k(
    const float* __restrict__ a2, const float* __restrict__ W3, const float* __restrict__ b3,
    float* __restrict__ Rest) {
  __shared__ float sa[64 * 30];
  for (int i = threadIdx.x; i < 64 * 30; i += 256) sa[i] = a2[i];
  long n0 = SZ_WHH + ((long)blockIdx.x * 256 + threadIdx.x) * 2;
  __syncthreads();
  if (n0 >= N_PSI) return;
  float2 w[30];
  #pragma unroll
  for (int l = 0; l < 30; ++l) w[l] = *(const float2*)(W3 + (long)l * N_PSI + n0);
  float2 bb = *(const float2*)(b3 + n0);
  long r = n0 - SZ_WHH;
  for (int b = 0; b < 64; ++b) {
    float a0 = bb.x, a1 = bb.y;
    const float* ab = &sa[b * 30];
    #pragma unroll
    for (int l = 0; l < 30; ++l) { float av = ab[l]; a0 += av * w[l].x; a1 += av * w[l].y; }
    *(float2*)(Rest + (long)b * REST_SZ + r) = make_float2(a0, a1);
  }
}

// ---------- decoder step: 512 threads, balanced phase B; int8 Whh ----------
__global__ __launch_bounds__(512, 2) void dec_step_q8i_k(
    const char* __restrict__ Q8,               // [B][1024][1024] int8
    const float* __restrict__ sdec,            // [16][1024][16]
    const unsigned short* __restrict__ gWhhB,  // [1024][2048] bf16 (z|r)
    const unsigned short* __restrict__ gxD,    // [T][B][2048] bf16 (incl gbias)
    const unsigned short* __restrict__ xWb,    // [T][B][1024] bf16
    const float* __restrict__ Rest,
    float* __restrict__ decS,                  // [B][T][1024]
    const float* __restrict__ pZr, const float* __restrict__ pRr, const float* __restrict__ pWr,
    float* __restrict__ pZw, float* __restrict__ pRw, float* __restrict__ pWw,
    int t) {
  int c = blockIdx.x & (NCH - 1);
  int sp = blockIdx.x >> 4;
  int b0 = sp * 2, b1 = b0 + 1;
  __shared__ float h0s[64], h1s[64];
  __shared__ float h0q[16][68], h1q[16][68];
  __shared__ float red[3][4][128];
  int v = threadIdx.x;
  {
    int q = v >> 7, idx = v & 127;
    int bb = (idx >> 6) ? b1 : b0;
    int k = c * 64 + (idx & 63);
    float sz = 0.f, sr = 0.f, sw = 0.f;
    if (t > 0) {
      #pragma unroll
      for (int cc = q * 4; cc < q * 4 + 4; ++cc) {
        long base = ((long)cc * 64 + bb) * 1024 + k;
        sz += pZr[base]; sr += pRr[base]; sw += pWr[base];
      }
    }
    red[0][q][idx] = sz; red[1][q][idx] = sr; red[2][q][idx] = sw;
  }
  __syncthreads();
  if (v < 128) {
    int hi = v >> 6;
    int bb = hi ? b1 : b0;
    int k = c * 64 + (v & 63);
    float sz = red[0][0][v] + red[0][1][v] + red[0][2][v] + red[0][3][v];
    float sr = red[1][0][v] + red[1][1][v] + red[1][2][v] + red[1][3][v];
    float sw = red[2][0][v] + red[2][1][v] + red[2][2][v] + red[2][3][v];
    long gb = ((long)t * 64 + bb) * 2048;
    float gz = b2f(gxD[gb + k]), gr = b2f(gxD[gb + 1024 + k]);
    float z = sigm(gz + sz);
    float r = sigm(gr + sr);
    float hW = sw + Rest[(long)bb * REST_SZ + R_BH + k];
    float xw = b2f(xWb[((long)t * 64 + bb) * 1024 + k]);
    float eta = tanhf(xw + r * tanhf(hW));
    float hold = (t > 0) ? decS[((long)bb * nT + (t - 1)) * 1024 + k] : 0.f;
    float hnew = z * hold + (1.f - z) * eta;
    decS[((long)bb * nT + t) * 1024 + k] = hnew;
    const float* sc = sdec + ((long)(bb >> 2) * 1024 + k) * 16;
    int row = v & 63;
    float (*hq)[68] = hi ? h1q : h0q;
    if (hi) h1s[row] = hnew; else h0s[row] = hnew;
    #pragma unroll
    for (int gg = 0; gg < 16; gg += 4) {
      float4 s4 = *(const float4*)(sc + gg);
      hq[gg + 0][row] = hnew * s4.x;
      hq[gg + 1][row] = hnew * s4.y;
      hq[gg + 2][row] = hnew * s4.z;
      hq[gg + 3][row] = hnew * s4.w;
    }
  }
  __syncthreads();
  // phase B (balanced): every thread: 4 gate-cols (us4) + 2 w-cols (char2), both samples
  if (t < nT - 1) {
    int c4 = v * 4;                 // 0..2047 over z|r
    int c2 = v * 2;                 // 0..1023 over w
    int g = c2 >> 6;                // 64-col scale group (uniform per 32 threads)
    const float* hq0 = h0q[g];
    const float* hq1 = h1q[g];
    float g0a[4] = {}, g1a[4] = {};
    float w0a[2] = {}, w1a[2] = {};
    const unsigned short* G = gWhhB + (long)(c * 64) * 2048 + c4;
    const char* Q0 = Q8 + (long)b0 * SZ_WHH + (long)(c * 64) * 1024 + c2;
    const char* Q1 = Q8 + (long)b1 * SZ_WHH + (long)(c * 64) * 1024 + c2;
    #pragma unroll 4
    for (int j = 0; j < 64; ++j) {
      us4 wg = *(const us4*)(G + (long)j * 2048);
      char2 q0 = *(const char2*)(Q0 + (long)j * 1024);
      char2 q1 = *(const char2*)(Q1 + (long)j * 1024);
      float hv0 = h0s[j], hv1 = h1s[j];
      #pragma unroll
      for (int q = 0; q < 4; ++q) {
        float f = b2f(wg[q]);
        g0a[q] += hv0 * f; g1a[q] += hv1 * f;
      }
      float hw0 = hq0[j], hw1 = hq1[j];
      w0a[0] += hw0 * (float)q0.x; w0a[1] += hw0 * (float)q0.y;
      w1a[0] += hw1 * (float)q1.x; w1a[1] += hw1 * (float)q1.y;
    }
    float* Pg = (c4 < 1024) ? pZw : pRw;
    int gcol = c4 & 1023;
    long i0 = ((long)c * 64 + b0) * 1024;
    long i1 = i0 + 1024;
    *(float4*)(Pg + i0 + gcol) = make_float4(g0a[0], g0a[1], g0a[2], g0a[3]);
    *(float4*)(Pg + i1 + gcol) = make_float4(g1a[0], g1a[1], g1a[2], g1a[3]);
    *(float2*)(pWw + i0 + c2) = make_float2(w0a[0], w0a[1]);
    *(float2*)(pWw + i1 + c2) = make_float2(w1a[0], w1a[1]);
  }
}

// ---------- readout (+ fused states copy for tg==7) ----------
__global__ __launch_bounds__(256) void readout_k(
    const float* __restrict__ dec_seq, const float* __restrict__ inputs,
    const float* __restrict__ Rest, float* __restrict__ yhats,
    float* __restrict__ states) {
  int b = blockIdx.x >> 3;
  int tg = blockIdx.x & 7;
  __shared__ float ss[8][1024];
  __shared__ float part[4][8][64];
  for (int i = threadIdx.x; i < 8 * 1024; i += 256)
    ss[i >> 10][i & 1023] = dec_seq[((long)b * nT + tg * 8 + (i >> 10)) * 1024 + (i & 1023)];
  __syncthreads();
  if (tg == 7) {
    for (int i = threadIdx.x; i < 1024; i += 256)
      states[(long)b * 1024 + i] = ss[7][i];
  }
  int m = threadIdx.x & 63, hq = threadIdx.x >> 6;
  const float* C = Rest + (long)b * REST_SZ + R_C;
  float acc[8] = {};
  for (int h = hq * 256; h < hq * 256 + 256; ++h) {
    float cv = C[(long)h * 64 + m];
    #pragma unroll
    for (int tt = 0; tt < 8; ++tt) acc[tt] += ss[tt][h] * cv;
  }
  #pragma unroll
  for (int tt = 0; tt < 8; ++tt) part[hq][tt][m] = acc[tt];
  __syncthreads();
  const float* D = Rest + (long)b * REST_SZ + R_D;
  for (int o = threadIdx.x; o < 512; o += 256) {
    int tt = o >> 6, mm = o & 63;
    float a = part[0][tt][mm] + part[1][tt][mm] + part[2][tt][mm] + part[3][tt][mm];
    long bt = (long)b * nT + tg * 8 + tt;
    if (mm < 8) {
      a += inputs[bt * 8 + mm];
    } else {
      #pragma unroll
      for (int i = 0; i < 8; ++i) a += inputs[bt * 8 + i] * D[i * 56 + (mm - 8)];
    }
    yhats[bt * 64 + mm] = a;
  }
}

extern "C" void kernel_launch(void* const* d_in, const int* in_sizes, int n_in,
                              void* d_out, int out_size, void* d_ws, size_t ws_size,
                              hipStream_t stream) {
  const float* inputs  = (const float*)d_in[0];
  const float* outputs = (const float*)d_in[1];
  const float* eps     = (const float*)d_in[2];
  const float* enc_Wih = (const float*)d_in[3];
  const float* enc_Whh = (const float*)d_in[4];
  const float* enc_bih = (const float*)d_in[5];
  const float* enc_bhh = (const float*)d_in[6];
  const float* to_mu   = (const float*)d_in[7];
  const float* to_lsig = (const float*)d_in[8];
  const float* lsig_b  = (const float*)d_in[9];
  const float* W1 = (const float*)d_in[10];
  const float* b1 = (const float*)d_in[11];
  const float* W2 = (const float*)d_in[12];
  const float* b2 = (const float*)d_in[13];
  const float* W3 = (const float*)d_in[14];
  const float* b3 = (const float*)d_in[15];
  const float* gWih  = (const float*)d_in[16];
  const float* gWhh  = (const float*)d_in[17];
  const float* gbias = (const float*)d_in[18];

  char* ws = (char*)d_ws;
  size_t off = 0;
  auto alloc = [&](size_t bytes) { size_t o = off; off = (off + bytes + 255) & ~(size_t)255; return o; };
  size_t oRest   = alloc(64ull * REST_SZ * 4);
  size_t oQ8     = alloc(64ull * SZ_WHH);
  size_t oSdec   = alloc(16ull * 1024 * 16 * 4);
  size_t ogWhhB  = alloc(1024ull * 2048 * 2);
  size_t oWtWhhB = alloc(1024ull * 3072 * 2);
  size_t oWtWihB = alloc(64ull * 3072 * 2);
  size_t ogxE    = alloc(64ull * 64 * 3072 * 2);
  size_t ogxD    = alloc(64ull * 64 * 2048 * 2);
  size_t oxWb    = alloc(64ull * 64 * 1024 * 2);
  size_t opA     = alloc((size_t)2 * PHALF * 4);
  size_t opB     = alloc((size_t)2 * PHALF * 4);
  size_t opC     = alloc((size_t)2 * PHALF * 4);
  size_t ohA     = alloc(64ull * 1024 * 4);
  size_t oDec    = alloc(64ull * 64 * 1024 * 4);
  size_t oA2     = alloc(64 * 30 * 4);
  (void)in_sizes; (void)n_in; (void)out_size; (void)ws_size;

  float*          Rest   = (float*)(ws + oRest);
  char*           Q8     = (char*)(ws + oQ8);
  float*          sdec   = (float*)(ws + oSdec);
  unsigned short* gWhhB  = (unsigned short*)(ws + ogWhhB);
  unsigned short* WtWhhB = (unsigned short*)(ws + oWtWhhB);
  unsigned short* WtWihB = (unsigned short*)(ws + oWtWihB);
  unsigned short* gxE    = (unsigned short*)(ws + ogxE);
  unsigned short* gxD    = (unsigned short*)(ws + ogxD);
  unsigned short* xWb    = (unsigned short*)(ws + oxWb);
  float* pA   = (float*)(ws + opA);
  float* pB   = (float*)(ws + opB);
  float* pC   = (float*)(ws + opC);
  float* hA   = (float*)(ws + ohA);
  float* decS = (float*)(ws + oDec);
  float* a2   = (float*)(ws + oA2);

  float* out    = (float*)d_out;
  float* out_yh = out;                 // 262144
  float* out_mu = out + 262144;        // 448
  float* out_ls = out + 262144 + 448;  // 448
  float* out_st = out + 262144 + 896;  // 65536

  // 1) weight preprocessing (bf16)
  transpose_bf16_k<<<dim3(32, 96), dim3(32, 8), 0, stream>>>(enc_Whh, WtWhhB, 3072, 1024);
  transpose_bf16_k<<<dim3(2, 96),  dim3(32, 8), 0, stream>>>(enc_Wih, WtWihB, 3072, 64);
  cvt_bf16_k<<<(int)((1024ull * 2048 + 255) / 256), 256, 0, stream>>>(gWhh, gWhhB, 1024 * 2048);

  // 2) bulk encoder gx
  enc_gx_k<<<dim3(12, 64), 256, 0, stream>>>(outputs, WtWihB, enc_bih, gxE);

  // 3) encoder recurrence (512-thread balanced steps)
  for (int t = 0; t < nT; ++t) {
    int rp = t & 1, wp = (t + 1) & 1;
    enc_step4_k<<<512, 512, 0, stream>>>(WtWhhB, gxE, enc_bhh, hA,
        pA + (size_t)rp * PHALF, pB + (size_t)rp * PHALF, pC + (size_t)rp * PHALF,
        pA + (size_t)wp * PHALF, pB + (size_t)wp * PHALF, pC + (size_t)wp * PHALF, t);
  }

  // 4) latent+hypernet, then fused psi->int8 + rest
  latent_hyper_k<<<64, 256, 0, stream>>>(hA, to_mu, to_lsig, lsig_b, eps,
                                         W1, b1, W2, b2, out_mu, out_ls, a2);
  psi_q8_k<<<4096, 256, 0, stream>>>(a2, W3, b3, Q8, sdec);
  psi_rest_k<<<(int)((REST_SZ / 2 + 255) / 256), 256, 0, stream>>>(a2, W3, b3, Rest);

  // 5) bulk decoder gx and x@Wih_b
  dec_gx_k<<<dim3(8, 64), 256, 0, stream>>>(inputs, gWih, gbias, gxD);
  xW_k<<<dim3(4, 64), 256, 0, stream>>>(inputs, Rest, xWb);

  // 6) decoder recurrence (512-thread balanced steps, int8 Whh)
  for (int t = 0; t < nT; ++t) {
    int rp = t & 1, wp = (t + 1) & 1;
    dec_step_q8i_k<<<512, 512, 0, stream>>>(Q8, sdec, gWhhB, gxD, xWb, Rest, decS,
        pA + (size_t)rp * PHALF, pB + (size_t)rp * PHALF, pC + (size_t)rp * PHALF,
        pA + (size_t)wp * PHALF, pB + (size_t)wp * PHALF, pC + (size_t)wp * PHALF, t);
  }

  // 7) readout (+ states fused)
  readout_k<<<512, 256, 0, stream>>>(decS, inputs, Rest, out_yh, out_st);
}

// Round 16
// 2747.828 us; speedup vs baseline: 1.0690x; 1.0690x over previous
//
#include <hip/hip_runtime.h>

// ---- problem constants ----
namespace {
constexpr int nT = 64;
constexpr int nK = 7;
constexpr long N_PSI = 1123776;
constexpr long SZ_WHH = 1048576;       // psi region 0: (1024,1024)
constexpr long REST_SZ = 75200;        // per-sample remaining psi elems
constexpr long R_BH = 0;               // (1024,)
constexpr long R_WIH = 1024;           // (8,1024)
constexpr long R_C = 9216;             // (1024,64)
constexpr long R_D = 74752;            // (8,56)
constexpr int NCH = 16;                // h-chunks per step
constexpr long PHALF = (long)NCH * 64 * 1024;  // one partial buffer (floats)
}

typedef __attribute__((ext_vector_type(4))) unsigned short us4;

__device__ __forceinline__ float b2f(unsigned short u) {
  return __uint_as_float(((unsigned int)u) << 16);
}
__device__ __forceinline__ unsigned short f2b(float f) {
  unsigned int u = __float_as_uint(f);
  return (unsigned short)((u + 0x7fffu + ((u >> 16) & 1u)) >> 16);
}
__device__ __forceinline__ float sigm(float x) { return 1.f / (1.f + __expf(-x)); }

// ---------- one-time: transpose (rows,cols) fp32 -> bf16 out[c*rows + r] ----------
__global__ void transpose_bf16_k(const float* __restrict__ in, unsigned short* __restrict__ out,
                                 int rows, int cols) {
  __shared__ float tile[32][33];
  int x = blockIdx.x * 32 + threadIdx.x;
  int y = blockIdx.y * 32 + threadIdx.y;
  #pragma unroll
  for (int i = 0; i < 32; i += 8)
    if ((y + i) < rows && x < cols) tile[threadIdx.y + i][threadIdx.x] = in[(long)(y + i) * cols + x];
  __syncthreads();
  x = blockIdx.y * 32 + threadIdx.x;
  y = blockIdx.x * 32 + threadIdx.y;
  #pragma unroll
  for (int i = 0; i < 32; i += 8)
    if ((y + i) < cols && x < rows) out[(long)(y + i) * rows + x] = f2b(tile[threadIdx.x][threadIdx.y + i]);
}

__global__ void cvt_bf16_k(const float* __restrict__ in, unsigned short* __restrict__ out, long n) {
  long i = (long)blockIdx.x * 256 + threadIdx.x;
  if (i < n) out[i] = f2b(in[i]);
}

// ---------- bulk: encoder gx ----------
__global__ __launch_bounds__(256) void enc_gx_k(const float* __restrict__ outputs,
                                                const unsigned short* __restrict__ WtWihB,
                                                const float* __restrict__ bih,
                                                unsigned short* __restrict__ gxE) {
  int g0 = blockIdx.x * 256;
  int btg = blockIdx.y;
  __shared__ unsigned short ws[64 * 256];
  __shared__ float xs[64][64];
  for (int i = threadIdx.x; i < 64 * 256; i += 256)
    ws[i] = WtWihB[(long)(i >> 8) * 3072 + g0 + (i & 255)];
  for (int i = threadIdx.x; i < 64 * 64; i += 256) {
    int idx = btg * 64 + (i >> 6);
    int t = idx >> 6, b = idx & 63;
    xs[i >> 6][i & 63] = outputs[((long)b * nT + t) * 64 + (i & 63)];
  }
  __syncthreads();
  float bihv = bih[g0 + threadIdx.x];
  for (int j = 0; j < 64; ++j) {
    int idx = btg * 64 + j;
    float acc = bihv;
    #pragma unroll 8
    for (int i = 0; i < 64; ++i) acc += xs[j][i] * b2f(ws[i * 256 + threadIdx.x]);
    gxE[(long)idx * 3072 + g0 + threadIdx.x] = f2b(acc);
  }
}

// ---------- bulk: decoder gx ----------
__global__ __launch_bounds__(256) void dec_gx_k(const float* __restrict__ inputs,
                                                const float* __restrict__ gWih,
                                                const float* __restrict__ gbias,
                                                unsigned short* __restrict__ gxD) {
  int g0 = blockIdx.x * 256;
  int btg = blockIdx.y;
  __shared__ float ws[8][256];
  __shared__ float xs[64][8];
  for (int i = threadIdx.x; i < 8 * 256; i += 256)
    ws[i >> 8][i & 255] = gWih[(long)(i >> 8) * 2048 + g0 + (i & 255)];
  for (int i = threadIdx.x; i < 64 * 8; i += 256) {
    int idx = btg * 64 + (i >> 3);
    int t = idx >> 6, b = idx & 63;
    xs[i >> 3][i & 7] = inputs[((long)b * nT + t) * 8 + (i & 7)];
  }
  __syncthreads();
  float bv = gbias[g0 + threadIdx.x];
  for (int j = 0; j < 64; ++j) {
    int idx = btg * 64 + j;
    float acc = bv;
    #pragma unroll
    for (int i = 0; i < 8; ++i) acc += xs[j][i] * ws[i][threadIdx.x];
    gxD[(long)idx * 2048 + g0 + threadIdx.x] = f2b(acc);
  }
}

// ---------- bulk: x @ Wih_b per sample ----------
__global__ __launch_bounds__(256) void xW_k(const float* __restrict__ inputs,
                                            const float* __restrict__ Rest,
                                            unsigned short* __restrict__ xWb) {
  int k0 = blockIdx.x * 256;
  int b = blockIdx.y;
  __shared__ float ws[8][256];
  __shared__ float xs[64][8];
  const float* RB = Rest + (long)b * REST_SZ + R_WIH;
  for (int i = threadIdx.x; i < 8 * 256; i += 256)
    ws[i >> 8][i & 255] = RB[(long)(i >> 8) * 1024 + k0 + (i & 255)];
  for (int i = threadIdx.x; i < 64 * 8; i += 256)
    xs[i >> 3][i & 7] = inputs[((long)b * nT + (i >> 3)) * 8 + (i & 7)];
  __syncthreads();
  for (int t = 0; t < 64; ++t) {
    float acc = 0.f;
    #pragma unroll
    for (int i = 0; i < 8; ++i) acc += xs[t][i] * ws[i][threadIdx.x];
    xWb[((long)t * 64 + b) * 1024 + k0 + threadIdx.x] = f2b(acc);
  }
}

// ---------- encoder step: 512 threads (r11 structure) ----------
__global__ __launch_bounds__(512, 2) void enc_step3_k(
    const unsigned short* __restrict__ W,       // [1024][3072] bf16 enc_Whh^T
    const unsigned short* __restrict__ gxE,     // [T][B][3072] bf16 (incl bih)
    const float* __restrict__ bhh,
    float* __restrict__ hEnc,                   // [B][1024] running h
    const float* __restrict__ pRr, const float* __restrict__ pZr, const float* __restrict__ pNr,
    float* __restrict__ pRw, float* __restrict__ pZw, float* __restrict__ pNw,
    int t) {
  int c = blockIdx.x & (NCH - 1);
  int sp = blockIdx.x >> 4;
  int b0 = sp * 2, b1 = b0 + 1;
  __shared__ float h0s[64], h1s[64];
  __shared__ float red[3][4][128];
  int v = threadIdx.x;
  {
    int q = v >> 7, idx = v & 127;
    int bb = (idx >> 6) ? b1 : b0;
    int e = c * 64 + (idx & 63);
    float sr = 0.f, sz = 0.f, sn = 0.f;
    if (t > 0) {
      #pragma unroll
      for (int cc = q * 4; cc < q * 4 + 4; ++cc) {
        long base = ((long)cc * 64 + bb) * 1024 + e;
        sr += pRr[base]; sz += pZr[base]; sn += pNr[base];
      }
    }
    red[0][q][idx] = sr; red[1][q][idx] = sz; red[2][q][idx] = sn;
  }
  __syncthreads();
  if (v < 128) {
    int hi = v >> 6;
    int bb = hi ? b1 : b0;
    int e = c * 64 + (v & 63);
    float sr = red[0][0][v] + red[0][1][v] + red[0][2][v] + red[0][3][v];
    float sz = red[1][0][v] + red[1][1][v] + red[1][2][v] + red[1][3][v];
    float sn = red[2][0][v] + red[2][1][v] + red[2][2][v] + red[2][3][v];
    long gb = ((long)t * 64 + bb) * 3072;
    float xr = b2f(gxE[gb + e]), xz = b2f(gxE[gb + 1024 + e]), xn = b2f(gxE[gb + 2048 + e]);
    float hr = sr + bhh[e], hz = sz + bhh[1024 + e], hn = sn + bhh[2048 + e];
    float r = sigm(xr + hr);
    float z = sigm(xz + hz);
    float n = tanhf(xn + r * hn);
    float hold = (t > 0) ? hEnc[(long)bb * 1024 + e] : 0.f;
    float hnew = (1.f - z) * n + z * hold;
    hEnc[(long)bb * 1024 + e] = hnew;
    if (hi) h1s[v & 63] = hnew; else h0s[v & 63] = hnew;
  }
  __syncthreads();
  if (t < nT - 1) {
    if (v < 256) {
      int e0 = v * 4;
      float ar0[4] = {}, az0[4] = {}, ar1[4] = {}, az1[4] = {};
      const unsigned short* Wb = W + (long)(c * 64) * 3072 + e0;
      #pragma unroll 4
      for (int j = 0; j < 64; ++j) {
        us4 wr = *(const us4*)(Wb + (long)j * 3072);
        us4 wz = *(const us4*)(Wb + (long)j * 3072 + 1024);
        float hv0 = h0s[j], hv1 = h1s[j];
        #pragma unroll
        for (int q = 0; q < 4; ++q) {
          float fr = b2f(wr[q]), fz = b2f(wz[q]);
          ar0[q] += hv0 * fr; az0[q] += hv0 * fz;
          ar1[q] += hv1 * fr; az1[q] += hv1 * fz;
        }
      }
      long i0 = ((long)c * 64 + b0) * 1024 + e0;
      long i1 = i0 + 1024;
      *(float4*)(pRw + i0) = make_float4(ar0[0], ar0[1], ar0[2], ar0[3]);
      *(float4*)(pZw + i0) = make_float4(az0[0], az0[1], az0[2], az0[3]);
      *(float4*)(pRw + i1) = make_float4(ar1[0], ar1[1], ar1[2], ar1[3]);
      *(float4*)(pZw + i1) = make_float4(az1[0], az1[1], az1[2], az1[3]);
    } else {
      int e0 = (v - 256) * 4;
      float an0[4] = {}, an1[4] = {};
      const unsigned short* Wb = W + (long)(c * 64) * 3072 + 2048 + e0;
      #pragma unroll 8
      for (int j = 0; j < 64; ++j) {
        us4 wn = *(const us4*)(Wb + (long)j * 3072);
        float hv0 = h0s[j], hv1 = h1s[j];
        #pragma unroll
        for (int q = 0; q < 4; ++q) {
          float fn = b2f(wn[q]);
          an0[q] += hv0 * fn; an1[q] += hv1 * fn;
        }
      }
      long i0 = ((long)c * 64 + b0) * 1024 + e0;
      long i1 = i0 + 1024;
      *(float4*)(pNw + i0) = make_float4(an0[0], an0[1], an0[2], an0[3]);
      *(float4*)(pNw + i1) = make_float4(an1[0], an1[1], an1[2], an1[3]);
    }
  }
}

// ---------- fused latent + hypernet layers 1-2 ----------
__global__ __launch_bounds__(256) void latent_hyper_k(
    const float* __restrict__ h_enc,
    const float* __restrict__ to_mu, const float* __restrict__ to_lsig,
    const float* __restrict__ lsig_bias, const float* __restrict__ eps,
    const float* __restrict__ W1, const float* __restrict__ b1,
    const float* __restrict__ W2, const float* __restrict__ b2,
    float* __restrict__ out_mu, float* __restrict__ out_lsig,
    float* __restrict__ a2out) {
  int b = blockIdx.x;
  __shared__ float hs[1024];
  __shared__ float zv[8];
  __shared__ float a1[1024];
  for (int i = threadIdx.x; i < 1024; i += 256) hs[i] = h_enc[b * 1024 + i];
  __syncthreads();
  int g = threadIdx.x >> 5, s = threadIdx.x & 31;
  if (g < nK) {
    float am = 0.f, as_ = 0.f;
    for (int h = s; h < 1024; h += 32) {
      float hv = hs[h];
      am += hv * to_mu[h * nK + g];
      as_ += hv * to_lsig[h * nK + g];
    }
    #pragma unroll
    for (int m = 16; m >= 1; m >>= 1) { am += __shfl_xor(am, m); as_ += __shfl_xor(as_, m); }
    if (s == 0) {
      float ls = as_ + lsig_bias[g];
      out_mu[b * nK + g] = am;
      out_lsig[b * nK + g] = ls;
      zv[g] = am + eps[b * nK + g] * __expf(ls);
    }
  }
  __syncthreads();
  for (int j = threadIdx.x; j < 1024; j += 256) {
    float acc = b1[j];
    #pragma unroll
    for (int i = 0; i < nK; ++i) acc += zv[i] * W1[i * 1024 + j];
    a1[j] = tanhf(acc);
  }
  __syncthreads();
  int l = threadIdx.x >> 3, s8 = threadIdx.x & 7;
  if (l < 30) {
    float acc = 0.f;
    for (int j = s8; j < 1024; j += 8) acc += a1[j] * W2[j * 30 + l];
    acc += __shfl_xor(acc, 4);
    acc += __shfl_xor(acc, 2);
    acc += __shfl_xor(acc, 1);
    if (s8 == 0) a2out[b * 30 + l] = acc + b2[l];
  }
}

// ---------- fused psi Whh: 1 col/thread (w registers resident), 4-sample-group scales ----------
// grid 4096: h = blk>>2 (psi row), q4 = blk&3 (col quarter); wave = 64 cols scale group
__global__ __launch_bounds__(256) void psi_q8_k(
    const float* __restrict__ a2, const float* __restrict__ W3, const float* __restrict__ b3,
    char* __restrict__ Q8, float* __restrict__ sdec /*[16][1024][16]*/) {
  __shared__ float sa[64 * 30];
  for (int i = threadIdx.x; i < 64 * 30; i += 256) sa[i] = a2[i];
  int h = blockIdx.x >> 2, q4 = blockIdx.x & 3;
  int wv = threadIdx.x >> 6, lane = threadIdx.x & 63;
  int g = q4 * 4 + wv;                        // 64-col scale group index (0..15)
  long n0 = (long)h * 1024 + q4 * 256 + threadIdx.x;
  float w[30];
  #pragma unroll
  for (int l = 0; l < 30; ++l) w[l] = W3[(long)l * N_PSI + n0];
  float bb = b3[n0];
  __syncthreads();
  for (int bq = 0; bq < 16; ++bq) {
    float vv[4];
    #pragma unroll
    for (int s = 0; s < 4; ++s) {
      int b = bq * 4 + s;
      float a0 = bb;
      const float* ab = &sa[b * 30];
      #pragma unroll
      for (int l = 0; l < 30; ++l) a0 += ab[l] * w[l];
      vv[s] = a0;
    }
    float m = fmaxf(fmaxf(fabsf(vv[0]), fabsf(vv[1])), fmaxf(fabsf(vv[2]), fabsf(vv[3])));
    #pragma unroll
    for (int d = 32; d >= 1; d >>= 1) m = fmaxf(m, __shfl_xor(m, d));
    float inv = (m > 0.f) ? 127.f / m : 0.f;
    #pragma unroll
    for (int s = 0; s < 4; ++s) {
      int q = __float2int_rn(vv[s] * inv);
      q = min(127, max(-127, q));
      Q8[(long)(bq * 4 + s) * SZ_WHH + n0] = (char)q;
    }
    if (lane == 0) sdec[((long)bq * 1024 + h) * 16 + g] = m * (1.f / 127.f);
  }
}

// ---------- psi rest region (fp32) ----------
__global__ __launch_bounds__(256) void psi_rest_k(
    const float* __restrict__ a2, const float* __restrict__ W3, const float* __restrict__ b3,
    float* __restrict__ Rest) {
  __shared__ float sa[64 * 30];
  for (int i = threadIdx.x; i < 64 * 30; i += 256) sa[i] = a2[i];
  long n0 = SZ_WHH + ((long)blockIdx.x * 256 + threadIdx.x) * 2;
  __syncthreads();
  if (n0 >= N_PSI) return;
  float2 w[30];
  #pragma unroll
  for (int l = 0; l < 30; ++l) w[l] = *(const float2*)(W3 + (long)l * N_PSI + n0);
  float2 bb = *(const float2*)(b3 + n0);
  long r = n0 - SZ_WHH;
  for (int b = 0; b < 64; ++b) {
    float a0 = bb.x, a1 = bb.y;
    const float* ab = &sa[b * 30];
    #pragma unroll
    for (int l = 0; l < 30; ++l) { float av = ab[l]; a0 += av * w[l].x; a1 += av * w[l].y; }
    *(float2*)(Rest + (long)b * REST_SZ + r) = make_float2(a0, a1);
  }
}

// ---------- decoder step: 512 threads; int8 Whh, 16-group scales folded into h ----------
__global__ __launch_bounds__(512, 2) void dec_step_q8h_k(
    const char* __restrict__ Q8,               // [B][1024][1024] int8
    const float* __restrict__ sdec,            // [16][1024][16] per-(bq,row,64-col group)
    const unsigned short* __restrict__ gWhhB,  // [1024][2048] bf16
    const unsigned short* __restrict__ gxD,    // [T][B][2048] bf16 (incl gbias)
    const unsigned short* __restrict__ xWb,    // [T][B][1024] bf16
    const float* __restrict__ Rest,
    float* __restrict__ decS,                  // [B][T][1024]
    const float* __restrict__ pZr, const float* __restrict__ pRr, const float* __restrict__ pWr,
    float* __restrict__ pZw, float* __restrict__ pRw, float* __restrict__ pWw,
    int t) {
  int c = blockIdx.x & (NCH - 1);
  int sp = blockIdx.x >> 4;
  int b0 = sp * 2, b1 = b0 + 1;
  __shared__ float h0s[64], h1s[64];
  __shared__ float h0q[16][68], h1q[16][68];   // padded: stride 68 avoids bank conflicts
  __shared__ float red[3][4][128];
  int v = threadIdx.x;
  {
    int q = v >> 7, idx = v & 127;
    int bb = (idx >> 6) ? b1 : b0;
    int k = c * 64 + (idx & 63);
    float sz = 0.f, sr = 0.f, sw = 0.f;
    if (t > 0) {
      #pragma unroll
      for (int cc = q * 4; cc < q * 4 + 4; ++cc) {
        long base = ((long)cc * 64 + bb) * 1024 + k;
        sz += pZr[base]; sr += pRr[base]; sw += pWr[base];
      }
    }
    red[0][q][idx] = sz; red[1][q][idx] = sr; red[2][q][idx] = sw;
  }
  __syncthreads();
  if (v < 128) {
    int hi = v >> 6;
    int bb = hi ? b1 : b0;
    int k = c * 64 + (v & 63);
    float sz = red[0][0][v] + red[0][1][v] + red[0][2][v] + red[0][3][v];
    float sr = red[1][0][v] + red[1][1][v] + red[1][2][v] + red[1][3][v];
    float sw = red[2][0][v] + red[2][1][v] + red[2][2][v] + red[2][3][v];
    long gb = ((long)t * 64 + bb) * 2048;
    float gz = b2f(gxD[gb + k]), gr = b2f(gxD[gb + 1024 + k]);
    float z = sigm(gz + sz);
    float r = sigm(gr + sr);
    float hW = sw + Rest[(long)bb * REST_SZ + R_BH + k];
    float xw = b2f(xWb[((long)t * 64 + bb) * 1024 + k]);
    float eta = tanhf(xw + r * tanhf(hW));
    float hold = (t > 0) ? decS[((long)bb * nT + (t - 1)) * 1024 + k] : 0.f;
    float hnew = z * hold + (1.f - z) * eta;
    decS[((long)bb * nT + t) * 1024 + k] = hnew;
    const float* sc = sdec + ((long)(bb >> 2) * 1024 + k) * 16;
    int row = v & 63;
    float (*hq)[68] = hi ? h1q : h0q;
    if (hi) h1s[row] = hnew; else h0s[row] = hnew;
    #pragma unroll
    for (int gg = 0; gg < 16; gg += 4) {
      float4 s4 = *(const float4*)(sc + gg);
      hq[gg + 0][row] = hnew * s4.x;
      hq[gg + 1][row] = hnew * s4.y;
      hq[gg + 2][row] = hnew * s4.z;
      hq[gg + 3][row] = hnew * s4.w;
    }
  }
  __syncthreads();
  if (t < nT - 1) {
    if (v < 256) {
      int k0 = v * 4;
      float az0[4] = {}, ar0[4] = {}, az1[4] = {}, ar1[4] = {};
      const unsigned short* G = gWhhB + (long)(c * 64) * 2048 + k0;
      #pragma unroll 4
      for (int j = 0; j < 64; ++j) {
        us4 wz = *(const us4*)(G + (long)j * 2048);
        us4 wr = *(const us4*)(G + (long)j * 2048 + 1024);
        float hv0 = h0s[j], hv1 = h1s[j];
        #pragma unroll
        for (int q = 0; q < 4; ++q) {
          float fz = b2f(wz[q]), fr = b2f(wr[q]);
          az0[q] += hv0 * fz; ar0[q] += hv0 * fr;
          az1[q] += hv1 * fz; ar1[q] += hv1 * fr;
        }
      }
      long i0 = ((long)c * 64 + b0) * 1024 + k0;
      long i1 = i0 + 1024;
      *(float4*)(pZw + i0) = make_float4(az0[0], az0[1], az0[2], az0[3]);
      *(float4*)(pRw + i0) = make_float4(ar0[0], ar0[1], ar0[2], ar0[3]);
      *(float4*)(pZw + i1) = make_float4(az1[0], az1[1], az1[2], az1[3]);
      *(float4*)(pRw + i1) = make_float4(ar1[0], ar1[1], ar1[2], ar1[3]);
    } else {
      int k0 = (v - 256) * 4;
      int g = k0 >> 6;                 // 64-col scale group (0..15)
      const float* hq0 = h0q[g];
      const float* hq1 = h1q[g];
      float aw0[4] = {}, aw1[4] = {};
      const char* Q0 = Q8 + (long)b0 * SZ_WHH + (long)(c * 64) * 1024 + k0;
      const char* Q1 = Q8 + (long)b1 * SZ_WHH + (long)(c * 64) * 1024 + k0;
      #pragma unroll 8
      for (int j = 0; j < 64; ++j) {
        char4 q0 = *(const char4*)(Q0 + (long)j * 1024);
        char4 q1 = *(const char4*)(Q1 + (long)j * 1024);
        float hv0 = hq0[j], hv1 = hq1[j];
        aw0[0] += hv0 * (float)q0.x; aw0[1] += hv0 * (float)q0.y;
        aw0[2] += hv0 * (float)q0.z; aw0[3] += hv0 * (float)q0.w;
        aw1[0] += hv1 * (float)q1.x; aw1[1] += hv1 * (float)q1.y;
        aw1[2] += hv1 * (float)q1.z; aw1[3] += hv1 * (float)q1.w;
      }
      long i0 = ((long)c * 64 + b0) * 1024 + k0;
      long i1 = i0 + 1024;
      *(float4*)(pWw + i0) = make_float4(aw0[0], aw0[1], aw0[2], aw0[3]);
      *(float4*)(pWw + i1) = make_float4(aw1[0], aw1[1], aw1[2], aw1[3]);
    }
  }
}

// ---------- readout (+ fused states copy for tg==7) ----------
__global__ __launch_bounds__(256) void readout_k(
    const float* __restrict__ dec_seq, const float* __restrict__ inputs,
    const float* __restrict__ Rest, float* __restrict__ yhats,
    float* __restrict__ states) {
  int b = blockIdx.x >> 3;
  int tg = blockIdx.x & 7;
  __shared__ float ss[8][1024];
  __shared__ float part[4][8][64];
  for (int i = threadIdx.x; i < 8 * 1024; i += 256)
    ss[i >> 10][i & 1023] = dec_seq[((long)b * nT + tg * 8 + (i >> 10)) * 1024 + (i & 1023)];
  __syncthreads();
  if (tg == 7) {
    for (int i = threadIdx.x; i < 1024; i += 256)
      states[(long)b * 1024 + i] = ss[7][i];
  }
  int m = threadIdx.x & 63, hq = threadIdx.x >> 6;
  const float* C = Rest + (long)b * REST_SZ + R_C;
  float acc[8] = {};
  for (int h = hq * 256; h < hq * 256 + 256; ++h) {
    float cv = C[(long)h * 64 + m];
    #pragma unroll
    for (int tt = 0; tt < 8; ++tt) acc[tt] += ss[tt][h] * cv;
  }
  #pragma unroll
  for (int tt = 0; tt < 8; ++tt) part[hq][tt][m] = acc[tt];
  __syncthreads();
  const float* D = Rest + (long)b * REST_SZ + R_D;
  for (int o = threadIdx.x; o < 512; o += 256) {
    int tt = o >> 6, mm = o & 63;
    float a = part[0][tt][mm] + part[1][tt][mm] + part[2][tt][mm] + part[3][tt][mm];
    long bt = (long)b * nT + tg * 8 + tt;
    if (mm < 8) {
      a += inputs[bt * 8 + mm];
    } else {
      #pragma unroll
      for (int i = 0; i < 8; ++i) a += inputs[bt * 8 + i] * D[i * 56 + (mm - 8)];
    }
    yhats[bt * 64 + mm] = a;
  }
}

extern "C" void kernel_launch(void* const* d_in, const int* in_sizes, int n_in,
                              void* d_out, int out_size, void* d_ws, size_t ws_size,
                              hipStream_t stream) {
  const float* inputs  = (const float*)d_in[0];
  const float* outputs = (const float*)d_in[1];
  const float* eps     = (const float*)d_in[2];
  const float* enc_Wih = (const float*)d_in[3];
  const float* enc_Whh = (const float*)d_in[4];
  const float* enc_bih = (const float*)d_in[5];
  const float* enc_bhh = (const float*)d_in[6];
  const float* to_mu   = (const float*)d_in[7];
  const float* to_lsig = (const float*)d_in[8];
  const float* lsig_b  = (const float*)d_in[9];
  const float* W1 = (const float*)d_in[10];
  const float* b1 = (const float*)d_in[11];
  const float* W2 = (const float*)d_in[12];
  const float* b2 = (const float*)d_in[13];
  const float* W3 = (const float*)d_in[14];
  const float* b3 = (const float*)d_in[15];
  const float* gWih  = (const float*)d_in[16];
  const float* gWhh  = (const float*)d_in[17];
  const float* gbias = (const float*)d_in[18];

  char* ws = (char*)d_ws;
  size_t off = 0;
  auto alloc = [&](size_t bytes) { size_t o = off; off = (off + bytes + 255) & ~(size_t)255; return o; };
  size_t oRest   = alloc(64ull * REST_SZ * 4);       // fp32 psi remainder (19 MB)
  size_t oQ8     = alloc(64ull * SZ_WHH);            // int8 Whh (67 MB)
  size_t oSdec   = alloc(16ull * 1024 * 16 * 4);     // per-(bq,row,group) scales (1 MB)
  size_t ogWhhB  = alloc(1024ull * 2048 * 2);        // bf16 gru_Whh
  size_t oWtWhhB = alloc(1024ull * 3072 * 2);        // bf16 enc_Whh^T
  size_t oWtWihB = alloc(64ull * 3072 * 2);          // bf16 enc_Wih^T
  size_t ogxE    = alloc(64ull * 64 * 3072 * 2);     // bf16 encoder gx (incl bih)
  size_t ogxD    = alloc(64ull * 64 * 2048 * 2);     // bf16 decoder gx (incl gbias)
  size_t oxWb    = alloc(64ull * 64 * 1024 * 2);     // bf16 x@Wih_b
  size_t opA     = alloc((size_t)2 * PHALF * 4);     // dbuf partials
  size_t opB     = alloc((size_t)2 * PHALF * 4);
  size_t opC     = alloc((size_t)2 * PHALF * 4);
  size_t ohA     = alloc(64ull * 1024 * 4);          // encoder running h
  size_t oDec    = alloc(64ull * 64 * 1024 * 4);
  size_t oA2     = alloc(64 * 30 * 4);
  (void)in_sizes; (void)n_in; (void)out_size; (void)ws_size;

  float*          Rest   = (float*)(ws + oRest);
  char*           Q8     = (char*)(ws + oQ8);
  float*          sdec   = (float*)(ws + oSdec);
  unsigned short* gWhhB  = (unsigned short*)(ws + ogWhhB);
  unsigned short* WtWhhB = (unsigned short*)(ws + oWtWhhB);
  unsigned short* WtWihB = (unsigned short*)(ws + oWtWihB);
  unsigned short* gxE    = (unsigned short*)(ws + ogxE);
  unsigned short* gxD    = (unsigned short*)(ws + ogxD);
  unsigned short* xWb    = (unsigned short*)(ws + oxWb);
  float* pA   = (float*)(ws + opA);
  float* pB   = (float*)(ws + opB);
  float* pC   = (float*)(ws + opC);
  float* hA   = (float*)(ws + ohA);
  float* decS = (float*)(ws + oDec);
  float* a2   = (float*)(ws + oA2);

  float* out    = (float*)d_out;
  float* out_yh = out;                 // 262144
  float* out_mu = out + 262144;        // 448
  float* out_ls = out + 262144 + 448;  // 448
  float* out_st = out + 262144 + 896;  // 65536

  // 1) weight preprocessing (bf16)
  transpose_bf16_k<<<dim3(32, 96), dim3(32, 8), 0, stream>>>(enc_Whh, WtWhhB, 3072, 1024);
  transpose_bf16_k<<<dim3(2, 96),  dim3(32, 8), 0, stream>>>(enc_Wih, WtWihB, 3072, 64);
  cvt_bf16_k<<<(int)((1024ull * 2048 + 255) / 256), 256, 0, stream>>>(gWhh, gWhhB, 1024 * 2048);

  // 2) bulk encoder gx
  enc_gx_k<<<dim3(12, 64), 256, 0, stream>>>(outputs, WtWihB, enc_bih, gxE);

  // 3) encoder recurrence (512-thread fused steps)
  for (int t = 0; t < nT; ++t) {
    int rp = t & 1, wp = (t + 1) & 1;
    enc_step3_k<<<512, 512, 0, stream>>>(WtWhhB, gxE, enc_bhh, hA,
        pA + (size_t)rp * PHALF, pB + (size_t)rp * PHALF, pC + (size_t)rp * PHALF,
        pA + (size_t)wp * PHALF, pB + (size_t)wp * PHALF, pC + (size_t)wp * PHALF, t);
  }

  // 4) latent+hypernet, then fused psi->int8 (register-resident W3) + rest
  latent_hyper_k<<<64, 256, 0, stream>>>(hA, to_mu, to_lsig, lsig_b, eps,
                                         W1, b1, W2, b2, out_mu, out_ls, a2);
  psi_q8_k<<<4096, 256, 0, stream>>>(a2, W3, b3, Q8, sdec);
  psi_rest_k<<<(int)((REST_SZ / 2 + 255) / 256), 256, 0, stream>>>(a2, W3, b3, Rest);

  // 5) bulk decoder gx and x@Wih_b
  dec_gx_k<<<dim3(8, 64), 256, 0, stream>>>(inputs, gWih, gbias, gxD);
  xW_k<<<dim3(4, 64), 256, 0, stream>>>(inputs, Rest, xWb);

  // 6) decoder recurrence (512-thread fused steps, int8 Whh, 16-group folded scales)
  for (int t = 0; t < nT; ++t) {
    int rp = t & 1, wp = (t + 1) & 1;
    dec_step_q8h_k<<<512, 512, 0, stream>>>(Q8, sdec, gWhhB, gxD, xWb, Rest, decS,
        pA + (size_t)rp * PHALF, pB + (size_t)rp * PHALF, pC + (size_t)rp * PHALF,
        pA + (size_t)wp * PHALF, pB + (size_t)wp * PHALF, pC + (size_t)wp * PHALF, t);
  }

  // 7) readout (+ states fused)
  readout_k<<<512, 256, 0, stream>>>(decS, inputs, Rest, out_yh, out_st);
}